// Round 4
// baseline (150.307 us; speedup 1.0000x reference)
//
#include <hip/hip_runtime.h>

#define NTYPES 50
#define NCATS  20
#define EDIM   64
#define BATCH  4
#define SEQL   256

// ll work decomposition: one block per (b, i, chunk-of-128-sources)
// per b: i=0..128 -> 1 block each (129), i=129..255 -> 2 blocks each (254) = 383
#define NB_PER_B     383
#define LL_BLOCKS    (BATCH * NB_PER_B)  // 1532
#define IT_BLOCKS    (BATCH * NTYPES)    // 200
#define IC_BLOCKS    (BATCH)             // 4
#define I0_BLOCKS    1
#define TOTAL_BLOCKS (LL_BLOCKS + IT_BLOCKS + IC_BLOCKS + I0_BLOCKS)  // 1737

// ws layout (4B units):
//  [0]=ll_total  [1..4]=int per b  [5]=I0  [6]=global completion counter (uint)
//  [8 .. 8+1024)      = lam partial per (b,i)  (float, atomicAdd)
//  [1032 .. 1032+1024) = per-event chunk counters (uint)
#define WS_LAM 8
#define WS_CNT 1032
#define WS_ZERO_BYTES ((WS_CNT + BATCH * SEQL) * 4)  // 8224

__device__ __forceinline__ float softplusf(float x) {
    return (x > 0.f) ? x + log1pf(__expf(-x)) : log1pf(__expf(x));
}

__device__ __forceinline__ float waveReduceSum(float v) {
    #pragma unroll
    for (int off = 32; off > 0; off >>= 1) v += __shfl_down(v, off, 64);
    return v;
}

__global__ __launch_bounds__(256) void hawkes_fused(
        const float* __restrict__ times,
        const int*   __restrict__ types,
        const int*   __restrict__ cats,
        const int*   __restrict__ Tp,
        const float* __restrict__ type_emb,
        const float* __restrict__ cat_emb,
        const float* __restrict__ amat,
        const float* __restrict__ bmat,
        const float* __restrict__ A,
        const float* __restrict__ P,
        const float* __restrict__ Bm,
        const float* __restrict__ Q,
        float* __restrict__ ws,
        float* __restrict__ out) {
    const int blk  = blockIdx.x;
    const int tid  = threadIdx.x;
    const int lane = tid & 63;
    const int wave = tid >> 6;

    __shared__ float red[4];
    __shared__ float sn[4][EDIM];

    if (blk < LL_BLOCKS) {
        // ---- log-likelihood: event (b, i), source chunk [s0, s1) ----
        const int b = blk / NB_PER_B;
        const int r = blk % NB_PER_B;
        int i, chunk, nchunks;
        if (r < 129) { i = r;              chunk = 0;      nchunks = 1; }
        else { int j = r - 129; i = 129 + (j >> 1); chunk = j & 1; nchunks = 2; }

        const int t = types[b * SEQL + i];
        const float te = type_emb[t * EDIM + lane];

        float acc = 0.f;
        int c = 0;
        if (i == 0) {
            if (wave == 0) acc = softplusf(te * amat[t * EDIM + lane]);
        } else {
            c = cats[b * SEQL + (i - 1)];
            const float ce  = cat_emb[c * EDIM + lane];
            const float t_i = times[b * SEQL + i];
            const int s0 = chunk * 128;
            const int s1 = (i < s0 + 128) ? i : (s0 + 128);
            const int ns = s1 - s0;
            // lane l (l<32) preloads indices for j=l: s = s0 + wave + 4*l
            const int sl = s0 + wave + 4 * (lane & 31);   // always <= 255
            const int   kv = types[b * SEQL + sl];
            const int   cv = cats [b * SEQL + sl];
            const float tv = t_i - times[b * SEQL + sl];
            const int nw = (ns > wave) ? ((ns - wave + 3) >> 2) : 0;
            #pragma unroll 4
            for (int j = 0; j < nw; ++j) {
                const int   k  = __shfl(kv, j);
                const int   cs = __shfl(cv, j);
                const float td = __shfl(tv, j);
                const float f  = type_emb[k  * EDIM + lane];
                const float g  = cat_emb [cs * EDIM + lane];
                const float Ak = A [(k  * NTYPES + t) * EDIM + lane];
                const float Pk = P [(k  * NTYPES + t) * EDIM + lane];
                const float Bk = Bm[(cs * NCATS  + c) * EDIM + lane];
                const float Qk = Q [(cs * NCATS  + c) * EDIM + lane];
                const float tf2 = te * f, cg2 = ce * g;
                acc += tf2 * Ak * __expf(-tf2 * Pk * td)
                     + cg2 * Bk * __expf(-cg2 * Qk * td);
            }
            // base term once per event (chunk 0 only)
            if (chunk == 0 && wave == 0)
                acc += te * (amat[t * EDIM + lane] + bmat[c * EDIM + lane]);
        }
        acc = waveReduceSum(acc);
        if (lane == 0) red[wave] = acc;
        __syncthreads();
        if (tid == 0) {
            const float part = red[0] + red[1] + red[2] + red[3];
            if (nchunks == 1) {
                atomicAdd(&ws[0], logf(part + 1e-16f) + part);
            } else {
                const int ev = b * SEQL + i;
                atomicAdd(&ws[WS_LAM + ev], part);
                __threadfence();
                unsigned int old = atomicAdd((unsigned int*)&ws[WS_CNT + ev], 1u);
                if (old == 1u) {   // I'm the last chunk for this event
                    __threadfence();
                    float lam = atomicAdd(&ws[WS_LAM + ev], 0.f);
                    atomicAdd(&ws[0], logf(lam + 1e-16f) + lam);
                }
            }
        }
    } else if (blk < LL_BLOCKS + IT_BLOCKS) {
        // ---- horizon integral, type channel, (b, t): 64 sources/wave ----
        const int bt = blk - LL_BLOCKS;
        const int b = bt / NTYPES, t = bt % NTYPES;
        const float Tf = (float)Tp[0];
        const float te = type_emb[t * EDIM + lane];
        const int sl = wave + 4 * lane;                  // lane l -> j=l, s<=255
        const int   kv = types[b * SEQL + sl];
        const float tv = Tf - times[b * SEQL + sl];
        float acc = 0.f;
        #pragma unroll 4
        for (int j = 0; j < 64; ++j) {
            const int   k  = __shfl(kv, j);
            const float td = __shfl(tv, j);
            const float f  = type_emb[k * EDIM + lane];
            const float Ak = A[(k * NTYPES + t) * EDIM + lane];
            const float Pk = P[(k * NTYPES + t) * EDIM + lane];
            const float tf2 = te * f;
            acc += tf2 * Ak * __expf(-tf2 * Pk * td);
        }
        acc = waveReduceSum(acc);
        if (lane == 0) red[wave] = acc;
        __syncthreads();
        if (tid == 0) atomicAdd(&ws[1 + b], red[0] + red[1] + red[2] + red[3]);
    } else if (blk < LL_BLOCKS + IT_BLOCKS + IC_BLOCKS) {
        // ---- horizon integral, category + base part, per b ----
        const int b = blk - LL_BLOCKS - IT_BLOCKS;
        const float Tf = (float)Tp[0];
        const int   lc = cats[b * SEQL + SEQL - 1];
        const float ce = cat_emb[lc * EDIM + lane];
        const int sl = wave + 4 * lane;
        const int   cv = cats[b * SEQL + sl];
        const float tv = Tf - times[b * SEQL + sl];
        float nacc = 0.f;
        #pragma unroll 4
        for (int j = 0; j < 64; ++j) {
            const int   cs = __shfl(cv, j);
            const float td = __shfl(tv, j);
            const float g  = cat_emb[cs * EDIM + lane];
            const float Bk = Bm[(cs * NCATS + lc) * EDIM + lane];
            const float Qk = Q [(cs * NCATS + lc) * EDIM + lane];
            const float cg2 = ce * g;
            nacc += cg2 * Bk * __expf(-cg2 * Qk * td);
        }
        sn[wave][lane] = nacc;
        __syncthreads();
        if (wave == 0) {
            float n_e = sn[0][lane] + sn[1][lane] + sn[2][lane] + sn[3][lane];
            float TA = 0.f, TS = 0.f;
            for (int t = 0; t < NTYPES; ++t) {
                const float tv2 = type_emb[t * EDIM + lane];
                TA += tv2 * amat[t * EDIM + lane];
                TS += tv2;
            }
            float term = TA + (bmat[lc * EDIM + lane] + n_e) * TS;
            term = waveReduceSum(term);
            if (lane == 0) atomicAdd(&ws[1 + b], term);
        }
    } else {
        // ---- I0 = sum softplus(type_emb*a) ----
        float acc = 0.f;
        for (int t = wave; t < NTYPES; t += 4)
            acc += softplusf(type_emb[t * EDIM + lane] * amat[t * EDIM + lane]);
        acc = waveReduceSum(acc);
        if (lane == 0) red[wave] = acc;
        __syncthreads();
        if (tid == 0) atomicAdd(&ws[5], red[0] + red[1] + red[2] + red[3]);
    }

    // ---- last-block-done finalize (dispatch-order independent) ----
    if (tid == 0) {
        __threadfence();  // release this block's ws contributions
        unsigned int old = atomicAdd((unsigned int*)&ws[6], 1u);
        if (old == TOTAL_BLOCKS - 1) {
            __threadfence();  // acquire
            float ll  = atomicAdd(&ws[0], 0.f);
            float i0  = atomicAdd(&ws[5], 0.f);
            float Tf  = (float)Tp[0];
            float tot = 0.f;
            for (int b = 0; b < BATCH; ++b) {
                float ib = atomicAdd(&ws[1 + b], 0.f);
                tot += ib * (Tf - times[b * SEQL + SEQL - 1]) + i0 * times[b * SEQL + 0];
            }
            out[0] = -(ll - tot);
        }
    }
}

extern "C" void kernel_launch(void* const* d_in, const int* in_sizes, int n_in,
                              void* d_out, int out_size, void* d_ws, size_t ws_size,
                              hipStream_t stream) {
    const float* times    = (const float*)d_in[0];
    const int*   types    = (const int*)  d_in[1];
    const int*   cats     = (const int*)  d_in[2];
    const int*   Tp       = (const int*)  d_in[3];
    const float* type_emb = (const float*)d_in[4];
    const float* cat_emb  = (const float*)d_in[5];
    const float* amat     = (const float*)d_in[6];
    const float* bmat     = (const float*)d_in[7];
    const float* A        = (const float*)d_in[8];
    const float* P        = (const float*)d_in[9];
    const float* Bm       = (const float*)d_in[10];
    const float* Q        = (const float*)d_in[11];
    float* out = (float*)d_out;
    float* ws  = (float*)d_ws;

    hipMemsetAsync(ws, 0, WS_ZERO_BYTES, stream);  // accumulators + counters

    hawkes_fused<<<TOTAL_BLOCKS, 256, 0, stream>>>(times, types, cats, Tp,
                                                   type_emb, cat_emb, amat, bmat,
                                                   A, P, Bm, Q, ws, out);
}

// Round 5
// 123.649 us; speedup vs baseline: 1.2156x; 1.2156x over previous
//
#include <hip/hip_runtime.h>

#define NTYPES 50
#define NCATS  20
#define EDIM   64
#define BATCH  4
#define SEQL   256

#define LL_BLOCKS    (BATCH * SEQL)     // 1024: one per (b,i)
#define IT_BLOCKS    (BATCH * NTYPES)   // 200 : one per (b,t)
#define IC_BLOCKS    (BATCH)            // 4
#define I0_BLOCKS    1
#define TOTAL_BLOCKS (LL_BLOCKS + IT_BLOCKS + IC_BLOCKS + I0_BLOCKS)  // 1229

// ws floats: [0..3]=ll per b, [4..7]=integral per b, [8]=I0, [9]=completion counter (uint)
#define WS_ZERO_BYTES 40

__device__ __forceinline__ float softplusf(float x) {
    return (x > 0.f) ? x + log1pf(__expf(-x)) : log1pf(__expf(x));
}

__device__ __forceinline__ float waveReduceSum(float v) {
    #pragma unroll
    for (int off = 32; off > 0; off >>= 1) v += __shfl_down(v, off, 64);
    return v;
}

__global__ __launch_bounds__(256) void hawkes_fused(
        const float* __restrict__ times,
        const int*   __restrict__ types,
        const int*   __restrict__ cats,
        const int*   __restrict__ Tp,
        const float* __restrict__ type_emb,
        const float* __restrict__ cat_emb,
        const float* __restrict__ amat,
        const float* __restrict__ bmat,
        const float* __restrict__ A,
        const float* __restrict__ P,
        const float* __restrict__ Bm,
        const float* __restrict__ Q,
        float* __restrict__ ws,
        float* __restrict__ out) {
    const int blk  = blockIdx.x;
    const int tid  = threadIdx.x;
    const int lane = tid & 63;
    const int wave = tid >> 6;

    // Packed premultiplied tables:
    //   sAP[k*64+e] = ( te_e*A[k,t,e]*f[k,e], -te_e*P[k,t,e]*f[k,e] )
    //   sBQ[c*64+e] = ( ce_e*Bm[c,lc,e]*g[c,e], -ce_e*Q[c,lc,e]*g[c,e] )
    //   sSeq[s]     = ( times[b,s], bitcast(type | cat<<16) )
    __shared__ float2 sAP[NTYPES * EDIM];   // 25.6 KB
    __shared__ float2 sBQ[NCATS * EDIM];    // 10.25 KB
    __shared__ float2 sSeq[SEQL];           // 2 KB
    __shared__ float  red[4];
    __shared__ float  sn[4][EDIM];          // 1 KB (IC only)

    if (blk < LL_BLOCKS) {
        // ---- log-likelihood term for event (b, i) ----
        const int b = blk >> 8, i = blk & 255;
        const int t = types[b * SEQL + i];
        if (i == 0) {
            if (wave == 0) {
                float sp = softplusf(type_emb[t * EDIM + lane] * amat[t * EDIM + lane]);
                sp = waveReduceSum(sp);
                if (lane == 0) atomicAdd(&ws[b], logf(sp + 1e-16f) + sp);
            }
        } else {
            const int   c   = cats[b * SEQL + (i - 1)];
            const float te  = type_emb[t * EDIM + lane];
            const float ce  = cat_emb[c * EDIM + lane];
            const float t_i = times[b * SEQL + i];
            for (int s = tid; s < SEQL; s += 256) {
                sSeq[s] = make_float2(times[b * SEQL + s],
                                      __int_as_float(types[b * SEQL + s] |
                                                     (cats[b * SEQL + s] << 16)));
            }
            for (int j = tid; j < NTYPES * EDIM; j += 256) {  // j&63 == lane
                const int   k = j >> 6;
                const float f = type_emb[j];
                const int   g = (k * NTYPES + t) * EDIM + lane;
                const float tf = te * f;
                sAP[j] = make_float2(tf * A[g], -tf * P[g]);
            }
            for (int j = tid; j < NCATS * EDIM; j += 256) {
                const int   cc = j >> 6;
                const float gg = cat_emb[j];
                const int   ix = (cc * NCATS + c) * EDIM + lane;
                const float cg = ce * gg;
                sBQ[j] = make_float2(cg * Bm[ix], -cg * Q[ix]);
            }
            __syncthreads();
            const int nj = (i > wave) ? ((i - wave + 3) >> 2) : 0;
            float acc = 0.f;
            #pragma unroll 4
            for (int j = 0; j < nj; ++j) {
                const int s = wave + (j << 2);
                const float2 sq = sSeq[s];
                const float  td = t_i - sq.x;
                const int    tc = __float_as_int(sq.y);
                const float2 ap = sAP[((tc & 0xffff) << 6) + lane];
                const float2 bq = sBQ[((tc >> 16) << 6) + lane];
                acc += ap.x * __expf(ap.y * td) + bq.x * __expf(bq.y * td);
            }
            if (wave == 0) acc += te * (amat[t * EDIM + lane] + bmat[c * EDIM + lane]);
            acc = waveReduceSum(acc);
            if (lane == 0) red[wave] = acc;
            __syncthreads();
            if (tid == 0) {
                const float lam = red[0] + red[1] + red[2] + red[3];
                atomicAdd(&ws[b], logf(lam + 1e-16f) + lam);
            }
        }
    } else if (blk < LL_BLOCKS + IT_BLOCKS) {
        // ---- horizon integral, type channel, (b, t) ----
        const int bt = blk - LL_BLOCKS;
        const int b = bt / NTYPES, t = bt % NTYPES;
        const float Tf = (float)Tp[0];
        const float te = type_emb[t * EDIM + lane];
        for (int s = tid; s < SEQL; s += 256) {
            sSeq[s] = make_float2(times[b * SEQL + s],
                                  __int_as_float(types[b * SEQL + s]));
        }
        for (int j = tid; j < NTYPES * EDIM; j += 256) {
            const int   k = j >> 6;
            const float f = type_emb[j];
            const int   g = (k * NTYPES + t) * EDIM + lane;
            const float tf = te * f;
            sAP[j] = make_float2(tf * A[g], -tf * P[g]);
        }
        __syncthreads();
        float acc = 0.f;
        #pragma unroll 4
        for (int j = 0; j < 64; ++j) {
            const int s = wave + (j << 2);
            const float2 sq = sSeq[s];
            const float  td = Tf - sq.x;
            const float2 ap = sAP[((__float_as_int(sq.y) & 0xffff) << 6) + lane];
            acc += ap.x * __expf(ap.y * td);
        }
        acc = waveReduceSum(acc);
        if (lane == 0) red[wave] = acc;
        __syncthreads();
        if (tid == 0) atomicAdd(&ws[4 + b], red[0] + red[1] + red[2] + red[3]);
    } else if (blk < LL_BLOCKS + IT_BLOCKS + IC_BLOCKS) {
        // ---- horizon integral, category + base, per b ----
        const int b = blk - LL_BLOCKS - IT_BLOCKS;
        const float Tf = (float)Tp[0];
        const int   lc = cats[b * SEQL + SEQL - 1];
        const float ce = cat_emb[lc * EDIM + lane];
        for (int s = tid; s < SEQL; s += 256) {
            sSeq[s] = make_float2(times[b * SEQL + s],
                                  __int_as_float(cats[b * SEQL + s]));
        }
        for (int j = tid; j < NCATS * EDIM; j += 256) {
            const int   cc = j >> 6;
            const float gg = cat_emb[j];
            const int   ix = (cc * NCATS + lc) * EDIM + lane;
            const float cg = ce * gg;
            sBQ[j] = make_float2(cg * Bm[ix], -cg * Q[ix]);
        }
        __syncthreads();
        float nacc = 0.f;
        #pragma unroll 4
        for (int j = 0; j < 64; ++j) {
            const int s = wave + (j << 2);
            const float2 sq = sSeq[s];
            const float  td = Tf - sq.x;
            const float2 bq = sBQ[(__float_as_int(sq.y) << 6) + lane];
            nacc += bq.x * __expf(bq.y * td);
        }
        sn[wave][lane] = nacc;
        __syncthreads();
        if (wave == 0) {
            float n_e = sn[0][lane] + sn[1][lane] + sn[2][lane] + sn[3][lane];
            float TA = 0.f, TS = 0.f;
            for (int t = 0; t < NTYPES; ++t) {
                const float tv = type_emb[t * EDIM + lane];
                TA += tv * amat[t * EDIM + lane];
                TS += tv;
            }
            float term = TA + (bmat[lc * EDIM + lane] + n_e) * TS;
            term = waveReduceSum(term);
            if (lane == 0) atomicAdd(&ws[4 + b], term);
        }
    } else {
        // ---- I0 ----
        float acc = 0.f;
        for (int t = wave; t < NTYPES; t += 4)
            acc += softplusf(type_emb[t * EDIM + lane] * amat[t * EDIM + lane]);
        acc = waveReduceSum(acc);
        if (lane == 0) red[wave] = acc;
        __syncthreads();
        if (tid == 0) atomicAdd(&ws[8], red[0] + red[1] + red[2] + red[3]);
    }

    // ---- last-block-done finalize: atomics-only protocol, NO __threadfence
    // (device-scope fence would write-back/invalidate the XCD L2; our cross-block
    //  state is exclusively atomic-accessed, so vmcnt-ordering suffices) ----
    if (tid == 0) {
        __asm__ __volatile__("s_waitcnt vmcnt(0)" ::: "memory");  // own atomics acked
        unsigned int old = atomicAdd((unsigned int*)&ws[9], 1u);
        if (old == TOTAL_BLOCKS - 1) {
            float ll = 0.f, tot = 0.f;
            const float Tf = (float)Tp[0];
            const float i0 = atomicAdd(&ws[8], 0.f);
            for (int b = 0; b < BATCH; ++b) {
                ll += atomicAdd(&ws[b], 0.f);
                float ib = atomicAdd(&ws[4 + b], 0.f);
                tot += ib * (Tf - times[b * SEQL + SEQL - 1]) + i0 * times[b * SEQL + 0];
            }
            out[0] = -(ll - tot);
        }
    }
}

extern "C" void kernel_launch(void* const* d_in, const int* in_sizes, int n_in,
                              void* d_out, int out_size, void* d_ws, size_t ws_size,
                              hipStream_t stream) {
    const float* times    = (const float*)d_in[0];
    const int*   types    = (const int*)  d_in[1];
    const int*   cats     = (const int*)  d_in[2];
    const int*   Tp       = (const int*)  d_in[3];
    const float* type_emb = (const float*)d_in[4];
    const float* cat_emb  = (const float*)d_in[5];
    const float* amat     = (const float*)d_in[6];
    const float* bmat     = (const float*)d_in[7];
    const float* A        = (const float*)d_in[8];
    const float* P        = (const float*)d_in[9];
    const float* Bm       = (const float*)d_in[10];
    const float* Q        = (const float*)d_in[11];
    float* out = (float*)d_out;
    float* ws  = (float*)d_ws;

    hipMemsetAsync(ws, 0, WS_ZERO_BYTES, stream);

    hawkes_fused<<<TOTAL_BLOCKS, 256, 0, stream>>>(times, types, cats, Tp,
                                                   type_emb, cat_emb, amat, bmat,
                                                   A, P, Bm, Q, ws, out);
}

// Round 6
// 96.839 us; speedup vs baseline: 1.5521x; 1.2768x over previous
//
#include <hip/hip_runtime.h>

#define NTYPES 50
#define NCATS  20
#define EDIM   64
#define BATCH  4
#define SEQL   256

// Blocks: 512 LL (b, pair{pr, 255-pr}) + 200 IT (b,t) + 4 IC (b) + 1 I0
#define LL_BLOCKS 512
#define IT_BLOCKS 200
#define IC_BLOCKS 4
#define TOTAL_BLOCKS 717

// ws float layout, every slot/counter on its own 128B (32-float) line:
//   value slot (target, g) at ws[(target*16+g)*32]; targets: 0=ll, 1..4=int_b, 5=I0
//   sub-counter g at ws[(96+g)*32]; top counter at ws[112*32]
#define SLOT(tgt, g) (((tgt) * 16 + (g)) * 32)
#define SUBC(g)      ((96 + (g)) * 32)
#define TOPC         (112 * 32)
#define WS_ZERO_BYTES ((112 * 32 + 1) * 4)

__device__ __forceinline__ float softplusf(float x) {
    return (x > 0.f) ? x + log1pf(__expf(-x)) : log1pf(__expf(x));
}

__device__ __forceinline__ float waveReduceSum(float v) {
    #pragma unroll
    for (int off = 32; off > 0; off >>= 1) v += __shfl_down(v, off, 64);
    return v;
}

__global__ __launch_bounds__(256) void hawkes_fused(
        const float* __restrict__ times,
        const int*   __restrict__ types,
        const int*   __restrict__ cats,
        const int*   __restrict__ Tp,
        const float* __restrict__ type_emb,
        const float* __restrict__ cat_emb,
        const float* __restrict__ amat,
        const float* __restrict__ bmat,
        const float* __restrict__ A,
        const float* __restrict__ P,
        const float* __restrict__ Bm,
        const float* __restrict__ Q,
        float* __restrict__ ws,
        float* __restrict__ out) {
    const int blk  = blockIdx.x;
    const int tid  = threadIdx.x;
    const int lane = tid & 63;
    const int wave = tid >> 6;
    const int g    = blk & 15;

    __shared__ float red1[4], red2[4];
    __shared__ float sn[4][EDIM];
    __shared__ float fin[96];
    __shared__ int   finflag;

    if (blk < LL_BLOCKS) {
        // ---- two events per block: i1 = pr (0..127), i2 = 255-pr (128..255) ----
        const int b  = blk >> 7;
        const int pr = blk & 127;
        const int i1 = pr, i2 = 255 - pr;
        const int base = b * SEQL;
        const int t1 = types[base + i1], t2 = types[base + i2];
        const int c2 = cats[base + i2 - 1];
        const int c1 = (i1 > 0) ? cats[base + i1 - 1] : 0;
        const float te1 = type_emb[t1 * EDIM + lane];
        const float te2 = type_emb[t2 * EDIM + lane];
        const float ce1 = cat_emb[c1 * EDIM + lane];
        const float ce2 = cat_emb[c2 * EDIM + lane];
        const float ti1 = times[base + i1], ti2 = times[base + i2];

        float acc1 = 0.f, acc2 = 0.f;
        // sources s ≡ wave (mod 4); s < i1 feeds both events, s in [i1,i2) only ev2
        #pragma unroll 4
        for (int s = wave; s < i1; s += 4) {
            const int   k  = types[base + s];
            const int   cs = cats [base + s];
            const float ts = times[base + s];
            const float f  = type_emb[k  * EDIM + lane];
            const float gg = cat_emb [cs * EDIM + lane];
            const float A1 = A [(k  * NTYPES + t1) * EDIM + lane];
            const float P1 = P [(k  * NTYPES + t1) * EDIM + lane];
            const float B1 = Bm[(cs * NCATS  + c1) * EDIM + lane];
            const float Q1 = Q [(cs * NCATS  + c1) * EDIM + lane];
            const float A2 = A [(k  * NTYPES + t2) * EDIM + lane];
            const float P2 = P [(k  * NTYPES + t2) * EDIM + lane];
            const float B2 = Bm[(cs * NCATS  + c2) * EDIM + lane];
            const float Q2 = Q [(cs * NCATS  + c2) * EDIM + lane];
            const float td1 = ti1 - ts, td2 = ti2 - ts;
            const float tf1 = te1 * f, cg1 = ce1 * gg;
            const float tf2 = te2 * f, cg2 = ce2 * gg;
            acc1 += tf1 * A1 * __expf(-tf1 * P1 * td1) + cg1 * B1 * __expf(-cg1 * Q1 * td1);
            acc2 += tf2 * A2 * __expf(-tf2 * P2 * td2) + cg2 * B2 * __expf(-cg2 * Q2 * td2);
        }
        const int n1 = (i1 > wave) ? ((i1 - wave + 3) >> 2) : 0;
        #pragma unroll 4
        for (int s = wave + 4 * n1; s < i2; s += 4) {
            const int   k  = types[base + s];
            const int   cs = cats [base + s];
            const float ts = times[base + s];
            const float f  = type_emb[k  * EDIM + lane];
            const float gg = cat_emb [cs * EDIM + lane];
            const float A2 = A [(k  * NTYPES + t2) * EDIM + lane];
            const float P2 = P [(k  * NTYPES + t2) * EDIM + lane];
            const float B2 = Bm[(cs * NCATS  + c2) * EDIM + lane];
            const float Q2 = Q [(cs * NCATS  + c2) * EDIM + lane];
            const float td2 = ti2 - ts;
            const float tf2 = te2 * f, cg2 = ce2 * gg;
            acc2 += tf2 * A2 * __expf(-tf2 * P2 * td2) + cg2 * B2 * __expf(-cg2 * Q2 * td2);
        }
        if (wave == 0) {
            if (i1 == 0) acc1 += softplusf(te1 * amat[t1 * EDIM + lane]);
            else         acc1 += te1 * (amat[t1 * EDIM + lane] + bmat[c1 * EDIM + lane]);
        } else if (wave == 1) {
            acc2 += te2 * (amat[t2 * EDIM + lane] + bmat[c2 * EDIM + lane]);
        }
        const float r1 = waveReduceSum(acc1);
        const float r2 = waveReduceSum(acc2);
        if (lane == 0) { red1[wave] = r1; red2[wave] = r2; }
        __syncthreads();
        if (tid == 0) {
            const float lam1 = red1[0] + red1[1] + red1[2] + red1[3];
            const float lam2 = red2[0] + red2[1] + red2[2] + red2[3];
            atomicAdd(&ws[SLOT(0, g)], logf(lam1 + 1e-16f) + lam1
                                     + logf(lam2 + 1e-16f) + lam2);
        }
    } else if (blk < LL_BLOCKS + IT_BLOCKS) {
        // ---- horizon integral, type channel, (b, t) ----
        const int bt = blk - LL_BLOCKS;
        const int b = bt / NTYPES, t = bt % NTYPES;
        const int base = b * SEQL;
        const float Tf = (float)Tp[0];
        const float te = type_emb[t * EDIM + lane];
        float acc = 0.f;
        #pragma unroll 4
        for (int s = wave; s < SEQL; s += 4) {
            const int   k  = types[base + s];
            const float td = Tf - times[base + s];
            const float f  = type_emb[k * EDIM + lane];
            const float Ak = A[(k * NTYPES + t) * EDIM + lane];
            const float Pk = P[(k * NTYPES + t) * EDIM + lane];
            const float tf = te * f;
            acc += tf * Ak * __expf(-tf * Pk * td);
        }
        const float r = waveReduceSum(acc);
        if (lane == 0) red1[wave] = r;
        __syncthreads();
        if (tid == 0)
            atomicAdd(&ws[SLOT(1 + b, g)], red1[0] + red1[1] + red1[2] + red1[3]);
    } else if (blk < LL_BLOCKS + IT_BLOCKS + IC_BLOCKS) {
        // ---- horizon integral, category + base, per b ----
        const int b = blk - LL_BLOCKS - IT_BLOCKS;
        const int base = b * SEQL;
        const float Tf = (float)Tp[0];
        const int   lc = cats[base + SEQL - 1];
        const float ce = cat_emb[lc * EDIM + lane];
        float nacc = 0.f;
        #pragma unroll 4
        for (int s = wave; s < SEQL; s += 4) {
            const int   cs = cats[base + s];
            const float td = Tf - times[base + s];
            const float gg = cat_emb[cs * EDIM + lane];
            const float Bk = Bm[(cs * NCATS + lc) * EDIM + lane];
            const float Qk = Q [(cs * NCATS + lc) * EDIM + lane];
            const float cg = ce * gg;
            nacc += cg * Bk * __expf(-cg * Qk * td);
        }
        sn[wave][lane] = nacc;
        __syncthreads();
        if (wave == 0) {
            const float n_e = sn[0][lane] + sn[1][lane] + sn[2][lane] + sn[3][lane];
            float TA = 0.f, TS = 0.f;
            for (int t = 0; t < NTYPES; ++t) {
                const float tv = type_emb[t * EDIM + lane];
                TA += tv * amat[t * EDIM + lane];
                TS += tv;
            }
            float term = TA + (bmat[lc * EDIM + lane] + n_e) * TS;
            term = waveReduceSum(term);
            if (lane == 0) atomicAdd(&ws[SLOT(1 + b, g)], term);
        }
    } else {
        // ---- I0 ----
        float acc = 0.f;
        for (int t = wave; t < NTYPES; t += 4)
            acc += softplusf(type_emb[t * EDIM + lane] * amat[t * EDIM + lane]);
        const float r = waveReduceSum(acc);
        if (lane == 0) red1[wave] = r;
        __syncthreads();
        if (tid == 0)
            atomicAdd(&ws[SLOT(5, g)], red1[0] + red1[1] + red1[2] + red1[3]);
    }

    // ---- hierarchical completion; atomics-only coherence ----
    if (tid == 0) {
        finflag = 0;
        __asm__ __volatile__("s_waitcnt vmcnt(0)" ::: "memory");
        const unsigned cnt_g = (unsigned)((TOTAL_BLOCKS + 15 - g) >> 4);
        unsigned old = atomicAdd((unsigned int*)&ws[SUBC(g)], 1u);
        if (old == cnt_g - 1u) {
            unsigned o2 = atomicAdd((unsigned int*)&ws[TOPC], 1u);
            if (o2 == 15u) finflag = 1;
        }
    }
    __syncthreads();
    if (finflag) {
        if (tid < 96) fin[tid] = atomicAdd(&ws[tid * 32], 0.f);
        __syncthreads();
        if (tid == 0) {
            float ll = 0.f, i0 = 0.f;
            for (int j = 0; j < 16; ++j) { ll += fin[j]; i0 += fin[80 + j]; }
            const float Tf = (float)Tp[0];
            float tot = 0.f;
            for (int b2 = 0; b2 < BATCH; ++b2) {
                float ib = 0.f;
                for (int j = 0; j < 16; ++j) ib += fin[(1 + b2) * 16 + j];
                tot += ib * (Tf - times[b2 * SEQL + SEQL - 1]) + i0 * times[b2 * SEQL];
            }
            out[0] = -(ll - tot);
        }
    }
}

extern "C" void kernel_launch(void* const* d_in, const int* in_sizes, int n_in,
                              void* d_out, int out_size, void* d_ws, size_t ws_size,
                              hipStream_t stream) {
    const float* times    = (const float*)d_in[0];
    const int*   types    = (const int*)  d_in[1];
    const int*   cats     = (const int*)  d_in[2];
    const int*   Tp       = (const int*)  d_in[3];
    const float* type_emb = (const float*)d_in[4];
    const float* cat_emb  = (const float*)d_in[5];
    const float* amat     = (const float*)d_in[6];
    const float* bmat     = (const float*)d_in[7];
    const float* A        = (const float*)d_in[8];
    const float* P        = (const float*)d_in[9];
    const float* Bm       = (const float*)d_in[10];
    const float* Q        = (const float*)d_in[11];
    float* out = (float*)d_out;
    float* ws  = (float*)d_ws;

    hipMemsetAsync(ws, 0, WS_ZERO_BYTES, stream);

    hawkes_fused<<<TOTAL_BLOCKS, 256, 0, stream>>>(times, types, cats, Tp,
                                                   type_emb, cat_emb, amat, bmat,
                                                   A, P, Bm, Q, ws, out);
}